// Round 5
// baseline (3209.130 us; speedup 1.0000x reference)
//
#include <hip/hip_runtime.h>
#include <math.h>

#define SS 512
#define BB 32
#define HH 256
#define G4 1024
#define TT 11
#define NEGV (-1000.0f)

typedef unsigned long long ull;

// ---------------- workspace layout (bytes) ----------------
static const size_t OFF_XEH   = 0;                          // 8,388,608  : xe_hi [16384][256] bf16
static const size_t OFF_XEL   = 8388608ull;                 // 8,388,608  : xe_lo
static const size_t OFF_XS    = 16777216ull;                // 134,217,728: xs [2][S][B][1024] f32
static const size_t OFF_H0    = OFF_XS + 134217728ull;      // 33,554,432 : h1 f32 (scan1 output)
static const size_t OFF_H1    = OFF_H0 + 33554432ull;       // 33,554,432 : h0_hi / h0_lo bf16 (scan0 writes directly)
static const size_t OFF_FEATS = OFF_H1 + 33554432ull;       // 720,896    : feats [B][S][11]
static const size_t OFF_HGRP  = OFF_FEATS + 720896ull;      // 262,144    : tagged h mailbox [2][2][32][256] u64
static const size_t OFF_W0H   = OFF_HGRP + 1048576ull;      // 1,048,576  : wih0 hi [2][1024][256] bf16
static const size_t OFF_W0L   = OFF_W0H + 1048576ull;       // 1,048,576
static const size_t OFF_W1H   = OFF_W0L + 1048576ull;       // 2,097,152  : wih1 hi [2][1024][512] bf16
static const size_t OFF_W1L   = OFF_W1H + 2097152ull;       // 2,097,152
// total ~226 MB

typedef __attribute__((ext_vector_type(8))) short short8;
typedef __attribute__((ext_vector_type(4))) float f32x4;

// fast transcendentals (1-2 ulp; outputs compared in bf16 w/ large threshold)
__device__ __forceinline__ float fsig(float x) {
  return __builtin_amdgcn_rcpf(1.f + __expf(-x));
}
__device__ __forceinline__ float ftanh(float x) {
  return 1.f - 2.f * __builtin_amdgcn_rcpf(__expf(2.f * x) + 1.f);
}

// raw barrier: drains LDS ops only (NO vmcnt(0) drain)
__device__ __forceinline__ void block_sync_lds() {
  asm volatile("s_waitcnt lgkmcnt(0)\n\ts_barrier" ::: "memory");
}

// ---------------- bf16 hi/lo split helpers ----------------
__device__ __forceinline__ unsigned short bfh(float x) {
  unsigned u = __float_as_uint(x);
  unsigned r = u + 0x7fffu + ((u >> 16) & 1u);   // RNE to bf16 (finite inputs)
  return (unsigned short)(r >> 16);
}
__device__ __forceinline__ void split1(float x, unsigned short& h, unsigned short& l) {
  h = bfh(x);
  float hf = __uint_as_float(((unsigned)h) << 16);
  l = bfh(x - hf);
}

// ---------------- embedding gather + split ----------------
__global__ void emb_kernel(const int* __restrict__ x, const float4* __restrict__ emb,
                           ushort4* __restrict__ xeh, ushort4* __restrict__ xel) {
  int idx = blockIdx.x * 256 + threadIdx.x;    // over B*S*64 float4-chunks
  int bs  = idx >> 6;
  int kq  = idx & 63;
  float4 v = emb[(size_t)x[bs] * 64 + kq];
  ushort4 h, l;
  split1(v.x, h.x, l.x); split1(v.y, h.y, l.y);
  split1(v.z, h.z, l.z); split1(v.w, h.w, l.w);
  xeh[idx] = h; xel[idx] = l;
}

// ---------------- generic f32 -> bf16 hi/lo split ----------------
__global__ void split_kernel(const float4* __restrict__ in, ushort4* __restrict__ oh,
                             ushort4* __restrict__ ol, int n4) {
  int i = blockIdx.x * 256 + threadIdx.x;
  if (i < n4) {
    float4 v = in[i];
    ushort4 h, l;
    split1(v.x, h.x, l.x); split1(v.y, h.y, l.y);
    split1(v.z, h.z, l.z); split1(v.w, h.w, l.w);
    oh[i] = h; ol[i] = l;
  }
}

// ---------------- input projection GEMM via split-bf16 MFMA ----------------
// (unchanged -- verified)
template<int K>
__global__ __launch_bounds__(256, 2)
void proj_mfma(const unsigned short* __restrict__ Ah_g, const unsigned short* __restrict__ Al_g,
               const unsigned short* __restrict__ Wh_g, const unsigned short* __restrict__ Wl_g,
               const float* __restrict__ bf, const float* __restrict__ bb,
               float* __restrict__ xs) {
  int tid = threadIdx.x;
  int bm  = blockIdx.x * 64;
  int bn  = blockIdx.y * 128;
  int dir = blockIdx.z;
  const unsigned short* Wh = Wh_g + (size_t)dir * 1024 * K;
  const unsigned short* Wl = Wl_g + (size_t)dir * 1024 * K;
  const float* bias = dir ? bb : bf;
  float* out = xs + (size_t)dir * (SS * BB * G4);

  __shared__ unsigned short AhS[64][40], AlS[64][40];
  __shared__ unsigned short BhS[128][40], BlS[128][40];

  int w = tid >> 6, lane = tid & 63;
  int wm = w >> 1, wn = w & 1;
  int fr = lane & 15, q8 = (lane >> 4) * 8;
  int ra = tid >> 2;
  int ck = (tid & 3) * 8;

  f32x4 acc[2][4];
  #pragma unroll
  for (int mt = 0; mt < 2; mt++)
    #pragma unroll
    for (int nt = 0; nt < 4; nt++) acc[mt][nt] = 0;

  for (int k0 = 0; k0 < K; k0 += 32) {
    __syncthreads();
    *(uint4*)&AhS[ra][ck] = *(const uint4*)(Ah_g + (size_t)(bm + ra) * K + k0 + ck);
    *(uint4*)&AlS[ra][ck] = *(const uint4*)(Al_g + (size_t)(bm + ra) * K + k0 + ck);
    *(uint4*)&BhS[ra][ck]      = *(const uint4*)(Wh + (size_t)(bn + ra) * K + k0 + ck);
    *(uint4*)&BhS[ra + 64][ck] = *(const uint4*)(Wh + (size_t)(bn + ra + 64) * K + k0 + ck);
    *(uint4*)&BlS[ra][ck]      = *(const uint4*)(Wl + (size_t)(bn + ra) * K + k0 + ck);
    *(uint4*)&BlS[ra + 64][ck] = *(const uint4*)(Wl + (size_t)(bn + ra + 64) * K + k0 + ck);
    __syncthreads();

    short8 ah[2], al[2], bh[4], bl[4];
    #pragma unroll
    for (int mt = 0; mt < 2; mt++) {
      ah[mt] = *(const short8*)&AhS[wm * 32 + mt * 16 + fr][q8];
      al[mt] = *(const short8*)&AlS[wm * 32 + mt * 16 + fr][q8];
    }
    #pragma unroll
    for (int nt = 0; nt < 4; nt++) {
      bh[nt] = *(const short8*)&BhS[wn * 64 + nt * 16 + fr][q8];
      bl[nt] = *(const short8*)&BlS[wn * 64 + nt * 16 + fr][q8];
    }
    #pragma unroll
    for (int mt = 0; mt < 2; mt++)
      #pragma unroll
      for (int nt = 0; nt < 4; nt++) {
        acc[mt][nt] = __builtin_amdgcn_mfma_f32_16x16x32_bf16(ah[mt], bh[nt], acc[mt][nt], 0, 0, 0);
        acc[mt][nt] = __builtin_amdgcn_mfma_f32_16x16x32_bf16(ah[mt], bl[nt], acc[mt][nt], 0, 0, 0);
        acc[mt][nt] = __builtin_amdgcn_mfma_f32_16x16x32_bf16(al[mt], bh[nt], acc[mt][nt], 0, 0, 0);
        acc[mt][nt] = __builtin_amdgcn_mfma_f32_16x16x32_bf16(al[mt], bl[nt], acc[mt][nt], 0, 0, 0);
      }
  }

  #pragma unroll
  for (int mt = 0; mt < 2; mt++)
    #pragma unroll
    for (int nt = 0; nt < 4; nt++) {
      int n  = bn + wn * 64 + nt * 16 + fr;
      float bv = bias[n];
      int mbase = bm + wm * 32 + mt * 16 + (lane >> 4) * 4;
      #pragma unroll
      for (int r = 0; r < 4; r++) {
        int mm = mbase + r;
        int b_ = mm >> 9;
        int s_ = mm & 511;
        out[(size_t)(s_ * BB + b_) * G4 + n] = acc[mt][nt][r] + bv;
      }
    }
}

// ---------------- recurrent scan (R13: clean vmcnt window around the poll) ----------------
// Structure = verified R9-v2 (grid (8,16,2), 4 waves, lane-half k-split,
// 1 barrier/step, tagged parity mailbox, agent-scope atomics). Changes vs R12:
//   1. Dead fast path removed (single mailbox, one atomic store).
//   2. xf prefetch issued right AFTER poll success (not after the store), so
//      the 4 HBM loads are never outstanding when the next poll's waitcnt
//      runs (vmcnt decrements in order -> they serialized ahead of the poll).
//   3. hout store deferred one step (register-buffered), written right after
//      the NEXT poll succeeds. At poll time the only outstanding vmem op is
//      the single mailbox store, whose ack overlaps peer visibility delay.
// Values, protocol, and write-sets are unchanged (hout writes move 1 step
// later + epilogue store for s=SS-1).
template<int BF16OUT>
__global__ __launch_bounds__(256, 1)
void scan_kernel(const float* __restrict__ xs,      // [2][S][B][1024]
                 const float* __restrict__ whhf, const float* __restrict__ whhb,
                 ull* __restrict__ hmb,             // [2][2][32][256] u64 mailbox
                 float* __restrict__ hout,          // [B*S][512] f32 (BF16OUT=0)
                 unsigned short* __restrict__ houth,// [B*S][512] bf16 hi (BF16OUT=1)
                 unsigned short* __restrict__ houtl)
{
  int tid  = threadIdx.x;
  int w    = tid >> 6;          // wave 0..3
  int lane = tid & 63;
  int cg   = blockIdx.x;        // cell group 0..7 (32 cells)
  int bg   = blockIdx.y;        // batch pair 0..15 (2 batches)
  int dir  = blockIdx.z;
  const float* xsd = xs + (size_t)dir * (SS * BB * G4);
  const float* whh = dir ? whhb : whhf;
  size_t dbase = (size_t)dir * 16384;   // [2][32][256] slots per dir

  __shared__ float h_sh[2][2][256];     // [parity][local batch][cell]

  int r    = lane & 31;         // row within wave's 32 rows: gate*8 + cellofs
  int ks   = lane >> 5;         // k-half: 0 -> k<128, 1 -> k>=128
  int g    = r >> 3;            // gate 0..3 (i,f,g,o)
  int c7   = r & 7;
  int cell = cg * 32 + w * 8 + c7;   // global cell of this lane's row
  int grow = g * 256 + cell;         // whh row

  // weights: 1 row x 128 k = 32 float4 in VGPRs
  float4 wreg[32];
  {
    const float* wp = whh + (size_t)grow * 256 + ks * 128;
    #pragma unroll
    for (int j = 0; j < 32; j++) wreg[j] = *(const float4*)(wp + j * 4);
  }

  int b0  = bg * 2;
  int col = tid & 255;          // polled cell column
  bool ul = (r < 8);            // update lane: owns (cell, batch b0+ks)
  int ub  = b0 + ks;
  float cst = 0.f;
  float xf[4];                  // x-projection for CURRENT step (prefetched)
  if (ul) {
    int t0 = dir ? (SS - 1) : 0;
    const float* xp = xsd + (size_t)(t0 * BB + ub) * G4 + cell;
    #pragma unroll
    for (int i = 0; i < 4; i++) xf[i] = xp[i * 256];
  }
  float hv_pend = 0.f;          // deferred hout value (h of step s-1)

  for (int s = 0; s < SS; ++s) {
    int p = s & 1;
    size_t mb = dbase + (size_t)(p * 32 + b0) * 256 + col;
    unsigned st = (unsigned)s;
    ull rv0, rv1;

    for (;;) {
      rv0 = __hip_atomic_load(hmb + mb,       __ATOMIC_RELAXED, __HIP_MEMORY_SCOPE_AGENT);
      rv1 = __hip_atomic_load(hmb + mb + 256, __ATOMIC_RELAXED, __HIP_MEMORY_SCOPE_AGENT);
      unsigned m = (((unsigned)(rv0 >> 32)) ^ st) | (((unsigned)(rv1 >> 32)) ^ st);
      if (__all(m == 0u)) break;
    }

    // xf prefetch for step s+1: issued NOW so it completes during the matvec
    // and is not outstanding at the next poll's waitcnt.
    float xfN[4] = {0.f, 0.f, 0.f, 0.f};
    if (ul && s + 1 < SS) {
      int tpn = dir ? (SS - 2 - s) : (s + 1);
      const float* xp = xsd + (size_t)(tpn * BB + ub) * G4 + cell;
      #pragma unroll
      for (int i = 0; i < 4; i++) xfN[i] = xp[i * 256];
    }
    // deferred hout store for step s-1 (acks during this step's compute)
    if (ul && s > 0) {
      int tprev = dir ? (SS - s) : (s - 1);
      size_t hidx = ((size_t)(ub * SS + tprev)) * 512 + dir * 256 + cell;
      if (BF16OUT) {
        unsigned short hh, hl;
        split1(hv_pend, hh, hl);
        houth[hidx] = hh; houtl[hidx] = hl;
      } else {
        hout[hidx] = hv_pend;
      }
    }

    h_sh[p][0][col] = __uint_as_float((unsigned)rv0);
    h_sh[p][1][col] = __uint_as_float((unsigned)rv1);
    block_sync_lds();

    // matvec: 1 row x 2 batches x 128 k per lane (h reads are wave-uniform
    // per half -> LDS broadcast, conflict-free)
    float acc0 = 0.f, acc1 = 0.f;
    const float* hb0 = &h_sh[p][0][ks * 128];
    const float* hb1 = &h_sh[p][1][ks * 128];
    #pragma unroll
    for (int j = 0; j < 32; j++) {
      float4 hv0 = *(const float4*)(hb0 + j * 4);
      float4 hv1 = *(const float4*)(hb1 + j * 4);
      float4 wv  = wreg[j];
      acc0 += wv.x * hv0.x + wv.y * hv0.y + wv.z * hv0.z + wv.w * hv0.w;
      acc1 += wv.x * hv1.x + wv.y * hv1.y + wv.z * hv1.z + wv.w * hv1.w;
    }
    // combine k-halves (lane <-> lane^32 hold same row, complementary k)
    acc0 += __shfl_xor(acc0, 32, 64);
    acc1 += __shfl_xor(acc1, 32, 64);
    // half ks carries batch b0+ks from here on
    float v = ks ? acc1 : acc0;
    // gather the 4 gates of this lane's cell from rows g*8+c in the same half
    float gv[4];
    #pragma unroll
    for (int gg = 0; gg < 4; gg++)
      gv[gg] = __shfl(v, (lane & 32) + gg * 8 + (lane & 7), 64);

    if (ul) {
      float ig = fsig(gv[0] + xf[0]);
      float fg = fsig(gv[1] + xf[1]);
      float gt = ftanh(gv[2] + xf[2]);
      float og = fsig(gv[3] + xf[3]);
      cst = fg * cst + ig * gt;
      float hv = og * ftanh(cst);
      ull tagw = ((ull)(unsigned)(s + 1) << 32) | (ull)__float_as_uint(hv);
      size_t mo = dbase + (size_t)((((s + 1) & 1) * 32 + ub)) * 256 + cell;
      __hip_atomic_store(hmb + mo, tagw,
                         __ATOMIC_RELAXED, __HIP_MEMORY_SCOPE_AGENT);
      hv_pend = hv;
      #pragma unroll
      for (int i = 0; i < 4; i++) xf[i] = xfN[i];
    }
  }

  // epilogue: hout store for the final step (s = SS-1)
  if (ul) {
    int tlast = dir ? 0 : (SS - 1);
    size_t hidx = ((size_t)(ub * SS + tlast)) * 512 + dir * 256 + cell;
    if (BF16OUT) {
      unsigned short hh, hl;
      split1(hv_pend, hh, hl);
      houth[hidx] = hh; houtl[hidx] = hl;
    } else {
      hout[hidx] = hv_pend;
    }
  }
}

// ---------------- emission features ----------------
__global__ void feats_kernel(const float* __restrict__ h1, const float* __restrict__ wout,
                             const float* __restrict__ bout, float* __restrict__ feats) {
  int bs = blockIdx.x;
  int lane = threadIdx.x;
  const float* hp = h1 + (size_t)bs * 512;
  float hv[8];
  #pragma unroll
  for (int i = 0; i < 8; i++) hv[i] = hp[lane + i * 64];
  #pragma unroll
  for (int t = 0; t < TT; t++) {
    const float* wp = wout + t * 512;
    float p = 0.f;
    #pragma unroll
    for (int i = 0; i < 8; i++) p += hv[i] * wp[lane + i * 64];
    #pragma unroll
    for (int off = 32; off >= 1; off >>= 1) p += __shfl_down(p, off, 64);
    if (lane == 0) feats[(size_t)bs * TT + t] = p + bout[t];
  }
}

// ---------------- Viterbi decode ----------------
__global__ void viterbi_kernel(const float* __restrict__ feats, const float* __restrict__ trans,
                               float* __restrict__ out) {
  int b = blockIdx.x;
  int lane = threadIdx.x;
  __shared__ float tr[121];
  __shared__ float fch[32 * TT];
  __shared__ unsigned char bp[SS][12];
  __shared__ unsigned char path[SS];
  for (int i = lane; i < 121; i += 64) tr[i] = trans[i];
  __syncthreads();
  int ln = lane < TT ? lane : (TT - 1);
  float trr[TT];
  #pragma unroll
  for (int p = 0; p < TT; p++) trr[p] = tr[ln * TT + p];
  float fv = (lane == 9) ? 0.f : NEGV;   // START = 9
  const float* fb = feats + (size_t)b * SS * TT;

  for (int s = 0; s < SS; s++) {
    if ((s & 31) == 0) {
      __syncthreads();
      for (int i = lane; i < 32 * TT; i += 64) fch[i] = fb[s * TT + i];
      __syncthreads();
    }
    float best = -3.0e38f; int arg = 0;
    #pragma unroll
    for (int p = 0; p < TT; p++) {
      float v = __shfl(fv, p, 64) + trr[p];
      if (v > best) { best = v; arg = p; }   // strict > keeps FIRST max (numpy argmax)
    }
    if (lane < TT) bp[s][lane] = (unsigned char)arg;
    fv = best + fch[(s & 31) * TT + ln];
  }
  float term = fv + tr[10 * TT + ln];        // STOP = 10
  float best = -3.0e38f; int arg = 0;
  #pragma unroll
  for (int p = 0; p < TT; p++) {
    float v = __shfl(term, p, 64);
    if (v > best) { best = v; arg = p; }
  }
  __syncthreads();
  if (lane == 0) {
    out[b] = best;
    int tg = arg;
    path[SS - 1] = (unsigned char)tg;
    for (int s = SS - 1; s >= 1; s--) {
      tg = bp[s][tg];
      path[s - 1] = (unsigned char)tg;
    }
  }
  __syncthreads();
  for (int i = lane; i < SS; i += 64) out[32 + b * SS + i] = (float)path[i];
}

// ---------------- launcher ----------------
extern "C" void kernel_launch(void* const* d_in, const int* in_sizes, int n_in,
                              void* d_out, int out_size, void* d_ws, size_t ws_size,
                              hipStream_t stream) {
  const int*   x     = (const int*)d_in[0];
  const float* emb   = (const float*)d_in[2];
  const float* wih0f = (const float*)d_in[3];
  const float* whh0f = (const float*)d_in[4];
  const float* b0f   = (const float*)d_in[5];
  const float* wih0b = (const float*)d_in[6];
  const float* whh0b = (const float*)d_in[7];
  const float* b0b   = (const float*)d_in[8];
  const float* wih1f = (const float*)d_in[9];
  const float* whh1f = (const float*)d_in[10];
  const float* b1f   = (const float*)d_in[11];
  const float* wih1b = (const float*)d_in[12];
  const float* whh1b = (const float*)d_in[13];
  const float* b1b   = (const float*)d_in[14];
  const float* wout  = (const float*)d_in[15];
  const float* bout  = (const float*)d_in[16];
  const float* trans = (const float*)d_in[17];

  char* ws = (char*)d_ws;
  unsigned short* xeh = (unsigned short*)(ws + OFF_XEH);
  unsigned short* xel = (unsigned short*)(ws + OFF_XEL);
  float* xs    = (float*)(ws + OFF_XS);
  float* h1    = (float*)(ws + OFF_H0);                     // scan1 f32 output
  unsigned short* h0h = (unsigned short*)(ws + OFF_H1);     // scan0 bf16 hi
  unsigned short* h0l = (unsigned short*)(ws + OFF_H1 + 16777216ull);
  float* feats = (float*)(ws + OFF_FEATS);
  ull* hmb = (ull*)(ws + OFF_HGRP);
  unsigned short* w0h = (unsigned short*)(ws + OFF_W0H);
  unsigned short* w0l = (unsigned short*)(ws + OFF_W0L);
  unsigned short* w1h = (unsigned short*)(ws + OFF_W1H);
  unsigned short* w1l = (unsigned short*)(ws + OFF_W1L);
  float* outp  = (float*)d_out;

  // embedding gather + hi/lo split
  emb_kernel<<<4096, 256, 0, stream>>>(x, (const float4*)emb, (ushort4*)xeh, (ushort4*)xel);
  // weight splits: wih0 [2][1024][256], wih1 [2][1024][512]
  split_kernel<<<256, 256, 0, stream>>>((const float4*)wih0f, (ushort4*)w0h, (ushort4*)w0l, 65536);
  split_kernel<<<256, 256, 0, stream>>>((const float4*)wih0b, (ushort4*)(w0h + 262144),
                                        (ushort4*)(w0l + 262144), 65536);
  split_kernel<<<512, 256, 0, stream>>>((const float4*)wih1f, (ushort4*)w1h, (ushort4*)w1l, 131072);
  split_kernel<<<512, 256, 0, stream>>>((const float4*)wih1b, (ushort4*)(w1h + 524288),
                                        (ushort4*)(w1l + 524288), 131072);

  proj_mfma<256><<<dim3(256, 8, 2), 256, 0, stream>>>(xeh, xel, w0h, w0l, b0f, b0b, xs);
  hipMemsetAsync(hmb, 0, 262144, stream);   // tag 0 == initial h(0) = 0, both parities
  scan_kernel<1><<<dim3(8, 16, 2), 256, 0, stream>>>(xs, whh0f, whh0b, hmb,
                                                     nullptr, h0h, h0l);

  proj_mfma<512><<<dim3(256, 8, 2), 256, 0, stream>>>(h0h, h0l, w1h, w1l, b1f, b1b, xs);
  hipMemsetAsync(hmb, 0, 262144, stream);
  scan_kernel<0><<<dim3(8, 16, 2), 256, 0, stream>>>(xs, whh1f, whh1b, hmb,
                                                     h1, nullptr, nullptr);

  feats_kernel<<<BB * SS, 64, 0, stream>>>(h1, wout, bout, feats);
  viterbi_kernel<<<BB, 64, 0, stream>>>(feats, trans, outp);
}

// Round 6
// 2933.474 us; speedup vs baseline: 1.0940x; 1.0940x over previous
//
#include <hip/hip_runtime.h>
#include <math.h>

#define SS 512
#define BB 32
#define HH 256
#define G4 1024
#define TT 11
#define NEGV (-1000.0f)

typedef unsigned long long ull;

// ---------------- workspace layout (bytes) ----------------
static const size_t OFF_XEH   = 0;                          // 8,388,608  : xe_hi [16384][256] bf16
static const size_t OFF_XEL   = 8388608ull;                 // 8,388,608  : xe_lo
static const size_t OFF_XS    = 16777216ull;                // 134,217,728: xs [2][S][B][1024] f32
static const size_t OFF_H0    = OFF_XS + 134217728ull;      // 33,554,432 : h1 f32 (scan1 output)
static const size_t OFF_H1    = OFF_H0 + 33554432ull;       // 33,554,432 : h0_hi / h0_lo bf16 (scan0 writes directly)
static const size_t OFF_FEATS = OFF_H1 + 33554432ull;       // 720,896    : feats [B][S][11]
static const size_t OFF_HGRP  = OFF_FEATS + 720896ull;      // 262,144    : tagged h mailbox [2][2][32][256] u64
static const size_t OFF_W0H   = OFF_HGRP + 1048576ull;      // 1,048,576  : wih0 hi [2][1024][256] bf16
static const size_t OFF_W0L   = OFF_W0H + 1048576ull;       // 1,048,576
static const size_t OFF_W1H   = OFF_W0L + 1048576ull;       // 2,097,152  : wih1 hi [2][1024][512] bf16
static const size_t OFF_W1L   = OFF_W1H + 2097152ull;       // 2,097,152
// total ~226 MB

typedef __attribute__((ext_vector_type(8))) short short8;
typedef __attribute__((ext_vector_type(4))) float f32x4;

// fast transcendentals (1-2 ulp; outputs compared in bf16 w/ large threshold)
__device__ __forceinline__ float fsig(float x) {
  return __builtin_amdgcn_rcpf(1.f + __expf(-x));
}
__device__ __forceinline__ float ftanh(float x) {
  return 1.f - 2.f * __builtin_amdgcn_rcpf(__expf(2.f * x) + 1.f);
}

// raw barrier: drains LDS ops only (NO vmcnt(0) drain)
__device__ __forceinline__ void block_sync_lds() {
  asm volatile("s_waitcnt lgkmcnt(0)\n\ts_barrier" ::: "memory");
}

// ---------------- bf16 hi/lo split helpers ----------------
__device__ __forceinline__ unsigned short bfh(float x) {
  unsigned u = __float_as_uint(x);
  unsigned r = u + 0x7fffu + ((u >> 16) & 1u);   // RNE to bf16 (finite inputs)
  return (unsigned short)(r >> 16);
}
__device__ __forceinline__ void split1(float x, unsigned short& h, unsigned short& l) {
  h = bfh(x);
  float hf = __uint_as_float(((unsigned)h) << 16);
  l = bfh(x - hf);
}

// ---------------- embedding gather + split ----------------
__global__ void emb_kernel(const int* __restrict__ x, const float4* __restrict__ emb,
                           ushort4* __restrict__ xeh, ushort4* __restrict__ xel) {
  int idx = blockIdx.x * 256 + threadIdx.x;    // over B*S*64 float4-chunks
  int bs  = idx >> 6;
  int kq  = idx & 63;
  float4 v = emb[(size_t)x[bs] * 64 + kq];
  ushort4 h, l;
  split1(v.x, h.x, l.x); split1(v.y, h.y, l.y);
  split1(v.z, h.z, l.z); split1(v.w, h.w, l.w);
  xeh[idx] = h; xel[idx] = l;
}

// ---------------- fused weight split (4 matrices, 1 launch) ----------------
// ranges (in float4 units): w0f 65536, w0b 65536, w1f 131072, w1b 131072.
__global__ void split4_kernel(const float4* __restrict__ w0f, const float4* __restrict__ w0b,
                              const float4* __restrict__ w1f, const float4* __restrict__ w1b,
                              ushort4* __restrict__ w0h, ushort4* __restrict__ w0l,
                              ushort4* __restrict__ w1h, ushort4* __restrict__ w1l) {
  int idx = blockIdx.x * 256 + threadIdx.x;    // 0 .. 393215
  const float4* src;
  ushort4 *dh, *dl;
  int i;
  if (idx < 131072) {
    if (idx < 65536) { src = w0f; i = idx;          dh = w0h;           dl = w0l; }
    else             { src = w0b; i = idx - 65536;  dh = w0h + 65536;   dl = w0l + 65536; }
  } else {
    if (idx < 262144){ src = w1f; i = idx - 131072; dh = w1h;           dl = w1l; }
    else             { src = w1b; i = idx - 262144; dh = w1h + 131072;  dl = w1l + 131072; }
  }
  float4 v = src[i];
  ushort4 h, l;
  split1(v.x, h.x, l.x); split1(v.y, h.y, l.y);
  split1(v.z, h.z, l.z); split1(v.w, h.w, l.w);
  dh[i] = h; dl[i] = l;
}

// ---------------- input projection GEMM via split-bf16 MFMA ----------------
// C[m][n] = sum_k A[m][k]*W[n][k] + bias[n], computed as (Ah+Al)(Wh+Wl) with
// 3 bf16 MFMA products (hh+hl+lh; the ll term is <= 2^-18 relative -- far
// below the bf16 compare threshold), fp32 accumulate.
template<int K>
__global__ __launch_bounds__(256, 2)
void proj_mfma(const unsigned short* __restrict__ Ah_g, const unsigned short* __restrict__ Al_g,
               const unsigned short* __restrict__ Wh_g, const unsigned short* __restrict__ Wl_g,
               const float* __restrict__ bf, const float* __restrict__ bb,
               float* __restrict__ xs) {
  int tid = threadIdx.x;
  int bm  = blockIdx.x * 64;
  int bn  = blockIdx.y * 128;
  int dir = blockIdx.z;
  const unsigned short* Wh = Wh_g + (size_t)dir * 1024 * K;
  const unsigned short* Wl = Wl_g + (size_t)dir * 1024 * K;
  const float* bias = dir ? bb : bf;
  float* out = xs + (size_t)dir * (SS * BB * G4);

  __shared__ unsigned short AhS[64][40], AlS[64][40];
  __shared__ unsigned short BhS[128][40], BlS[128][40];

  int w = tid >> 6, lane = tid & 63;
  int wm = w >> 1, wn = w & 1;
  int fr = lane & 15, q8 = (lane >> 4) * 8;
  int ra = tid >> 2;
  int ck = (tid & 3) * 8;

  f32x4 acc[2][4];
  #pragma unroll
  for (int mt = 0; mt < 2; mt++)
    #pragma unroll
    for (int nt = 0; nt < 4; nt++) acc[mt][nt] = 0;

  for (int k0 = 0; k0 < K; k0 += 32) {
    __syncthreads();
    *(uint4*)&AhS[ra][ck] = *(const uint4*)(Ah_g + (size_t)(bm + ra) * K + k0 + ck);
    *(uint4*)&AlS[ra][ck] = *(const uint4*)(Al_g + (size_t)(bm + ra) * K + k0 + ck);
    *(uint4*)&BhS[ra][ck]      = *(const uint4*)(Wh + (size_t)(bn + ra) * K + k0 + ck);
    *(uint4*)&BhS[ra + 64][ck] = *(const uint4*)(Wh + (size_t)(bn + ra + 64) * K + k0 + ck);
    *(uint4*)&BlS[ra][ck]      = *(const uint4*)(Wl + (size_t)(bn + ra) * K + k0 + ck);
    *(uint4*)&BlS[ra + 64][ck] = *(const uint4*)(Wl + (size_t)(bn + ra + 64) * K + k0 + ck);
    __syncthreads();

    short8 ah[2], al[2], bh[4], bl[4];
    #pragma unroll
    for (int mt = 0; mt < 2; mt++) {
      ah[mt] = *(const short8*)&AhS[wm * 32 + mt * 16 + fr][q8];
      al[mt] = *(const short8*)&AlS[wm * 32 + mt * 16 + fr][q8];
    }
    #pragma unroll
    for (int nt = 0; nt < 4; nt++) {
      bh[nt] = *(const short8*)&BhS[wn * 64 + nt * 16 + fr][q8];
      bl[nt] = *(const short8*)&BlS[wn * 64 + nt * 16 + fr][q8];
    }
    #pragma unroll
    for (int mt = 0; mt < 2; mt++)
      #pragma unroll
      for (int nt = 0; nt < 4; nt++) {
        acc[mt][nt] = __builtin_amdgcn_mfma_f32_16x16x32_bf16(ah[mt], bh[nt], acc[mt][nt], 0, 0, 0);
        acc[mt][nt] = __builtin_amdgcn_mfma_f32_16x16x32_bf16(ah[mt], bl[nt], acc[mt][nt], 0, 0, 0);
        acc[mt][nt] = __builtin_amdgcn_mfma_f32_16x16x32_bf16(al[mt], bh[nt], acc[mt][nt], 0, 0, 0);
      }
  }

  #pragma unroll
  for (int mt = 0; mt < 2; mt++)
    #pragma unroll
    for (int nt = 0; nt < 4; nt++) {
      int n  = bn + wn * 64 + nt * 16 + fr;
      float bv = bias[n];
      int mbase = bm + wm * 32 + mt * 16 + (lane >> 4) * 4;
      #pragma unroll
      for (int r = 0; r < 4; r++) {
        int mm = mbase + r;
        int b_ = mm >> 9;
        int s_ = mm & 511;
        out[(size_t)(s_ * BB + b_) * G4 + n] = acc[mt][nt][r] + bv;
      }
    }
}

// ---------------- recurrent scan (R14: proven R12 loop, single mailbox) ----------------
// Structure/order = the verified 1240us R12 kernel: poll -> LDS stage ->
// barrier -> matvec -> shfl gather -> gates -> mailbox store -> hout store ->
// xf prefetch (issued LAST: full-step prefetch distance; its drain at the
// next poll overlaps time spent waiting for producers anyway -- R13 proved
// moving it earlier starves the gate path).
// Changes vs R12: dead fast-path removed (single agent-atomic mailbox);
// TAGOFF template (scan1 uses tags 1000+s so no re-memset is needed: scan0's
// full-coverage store of tags <=512 can never false-match 1000+s); poll
// skipped at s==0 (h(0)=0 known).
template<int BF16OUT, int TAGOFF>
__global__ __launch_bounds__(256, 1)
void scan_kernel(const float* __restrict__ xs,      // [2][S][B][1024]
                 const float* __restrict__ whhf, const float* __restrict__ whhb,
                 ull* __restrict__ hmb,             // [2][2][32][256] u64 mailbox
                 float* __restrict__ hout,          // [B*S][512] f32 (BF16OUT=0)
                 unsigned short* __restrict__ houth,// [B*S][512] bf16 hi (BF16OUT=1)
                 unsigned short* __restrict__ houtl)
{
  int tid  = threadIdx.x;
  int w    = tid >> 6;          // wave 0..3
  int lane = tid & 63;
  int cg   = blockIdx.x;        // cell group 0..7 (32 cells)
  int bg   = blockIdx.y;        // batch pair 0..15 (2 batches)
  int dir  = blockIdx.z;
  const float* xsd = xs + (size_t)dir * (SS * BB * G4);
  const float* whh = dir ? whhb : whhf;
  size_t dbase = (size_t)dir * 16384;   // [2][32][256] slots per dir

  __shared__ float h_sh[2][2][256];     // [parity][local batch][cell]

  int r    = lane & 31;         // row within wave's 32 rows: gate*8 + cellofs
  int ks   = lane >> 5;         // k-half: 0 -> k<128, 1 -> k>=128
  int g    = r >> 3;            // gate 0..3 (i,f,g,o)
  int c7   = r & 7;
  int cell = cg * 32 + w * 8 + c7;   // global cell of this lane's row
  int grow = g * 256 + cell;         // whh row

  // weights: 1 row x 128 k = 32 float4 in VGPRs
  float4 wreg[32];
  {
    const float* wp = whh + (size_t)grow * 256 + ks * 128;
    #pragma unroll
    for (int j = 0; j < 32; j++) wreg[j] = *(const float4*)(wp + j * 4);
  }

  int b0  = bg * 2;
  int col = tid & 255;          // polled cell column
  bool ul = (r < 8);            // update lane: owns (cell, batch b0+ks)
  int ub  = b0 + ks;
  float cst = 0.f;
  float xf[4];                  // prefetched x-projection (4 gates)
  if (ul) {
    int t0 = dir ? (SS - 1) : 0;
    const float* xp = xsd + (size_t)(t0 * BB + ub) * G4 + cell;
    #pragma unroll
    for (int i = 0; i < 4; i++) xf[i] = xp[i * 256];
  }

  for (int s = 0; s < SS; ++s) {
    int p = s & 1;
    size_t mb = dbase + (size_t)(p * 32 + b0) * 256 + col;
    ull rv0 = 0, rv1 = 0;

    if (s > 0) {
      unsigned st = (unsigned)(TAGOFF + s);
      for (;;) {
        rv0 = __hip_atomic_load(hmb + mb,       __ATOMIC_RELAXED, __HIP_MEMORY_SCOPE_AGENT);
        rv1 = __hip_atomic_load(hmb + mb + 256, __ATOMIC_RELAXED, __HIP_MEMORY_SCOPE_AGENT);
        unsigned m = (((unsigned)(rv0 >> 32)) ^ st) | (((unsigned)(rv1 >> 32)) ^ st);
        if (__all(m == 0u)) break;
      }
    }

    h_sh[p][0][col] = __uint_as_float((unsigned)rv0);
    h_sh[p][1][col] = __uint_as_float((unsigned)rv1);
    block_sync_lds();

    // matvec: 1 row x 2 batches x 128 k per lane (h reads are wave-uniform
    // per half -> LDS broadcast, conflict-free)
    float acc0 = 0.f, acc1 = 0.f;
    const float* hb0 = &h_sh[p][0][ks * 128];
    const float* hb1 = &h_sh[p][1][ks * 128];
    #pragma unroll
    for (int j = 0; j < 32; j++) {
      float4 hv0 = *(const float4*)(hb0 + j * 4);
      float4 hv1 = *(const float4*)(hb1 + j * 4);
      float4 wv  = wreg[j];
      acc0 += wv.x * hv0.x + wv.y * hv0.y + wv.z * hv0.z + wv.w * hv0.w;
      acc1 += wv.x * hv1.x + wv.y * hv1.y + wv.z * hv1.z + wv.w * hv1.w;
    }
    // combine k-halves (lane <-> lane^32 hold same row, complementary k)
    acc0 += __shfl_xor(acc0, 32, 64);
    acc1 += __shfl_xor(acc1, 32, 64);
    // half ks carries batch b0+ks from here on
    float v = ks ? acc1 : acc0;
    // gather the 4 gates of this lane's cell from rows g*8+c in the same half
    float gv[4];
    #pragma unroll
    for (int gg = 0; gg < 4; gg++)
      gv[gg] = __shfl(v, (lane & 32) + gg * 8 + (lane & 7), 64);

    if (ul) {
      float ig = fsig(gv[0] + xf[0]);
      float fg = fsig(gv[1] + xf[1]);
      float gt = ftanh(gv[2] + xf[2]);
      float og = fsig(gv[3] + xf[3]);
      cst = fg * cst + ig * gt;
      float hv = og * ftanh(cst);
      ull tagw = ((ull)(unsigned)(TAGOFF + s + 1) << 32) | (ull)__float_as_uint(hv);
      size_t mo = dbase + (size_t)((((s + 1) & 1) * 32 + ub)) * 256 + cell;
      __hip_atomic_store(hmb + mo, tagw,
                         __ATOMIC_RELAXED, __HIP_MEMORY_SCOPE_AGENT);
      int tcur = dir ? (SS - 1 - s) : s;
      size_t hidx = ((size_t)(ub * SS + tcur)) * 512 + dir * 256 + cell;
      if (BF16OUT) {
        unsigned short hh, hl;
        split1(hv, hh, hl);
        houth[hidx] = hh; houtl[hidx] = hl;
      } else {
        hout[hidx] = hv;
      }
      if (s + 1 < SS) {
        int tpn = dir ? (SS - 2 - s) : (s + 1);
        const float* xp = xsd + (size_t)(tpn * BB + ub) * G4 + cell;
        #pragma unroll
        for (int i = 0; i < 4; i++) xf[i] = xp[i * 256];
      }
    }
  }
}

// ---------------- emission features ----------------
__global__ void feats_kernel(const float* __restrict__ h1, const float* __restrict__ wout,
                             const float* __restrict__ bout, float* __restrict__ feats) {
  int bs = blockIdx.x;
  int lane = threadIdx.x;
  const float* hp = h1 + (size_t)bs * 512;
  float hv[8];
  #pragma unroll
  for (int i = 0; i < 8; i++) hv[i] = hp[lane + i * 64];
  #pragma unroll
  for (int t = 0; t < TT; t++) {
    const float* wp = wout + t * 512;
    float p = 0.f;
    #pragma unroll
    for (int i = 0; i < 8; i++) p += hv[i] * wp[lane + i * 64];
    #pragma unroll
    for (int off = 32; off >= 1; off >>= 1) p += __shfl_down(p, off, 64);
    if (lane == 0) feats[(size_t)bs * TT + t] = p + bout[t];
  }
}

// ---------------- Viterbi decode ----------------
__global__ void viterbi_kernel(const float* __restrict__ feats, const float* __restrict__ trans,
                               float* __restrict__ out) {
  int b = blockIdx.x;
  int lane = threadIdx.x;
  __shared__ float tr[121];
  __shared__ float fch[32 * TT];
  __shared__ unsigned char bp[SS][12];
  __shared__ unsigned char path[SS];
  for (int i = lane; i < 121; i += 64) tr[i] = trans[i];
  __syncthreads();
  int ln = lane < TT ? lane : (TT - 1);
  float trr[TT];
  #pragma unroll
  for (int p = 0; p < TT; p++) trr[p] = tr[ln * TT + p];
  float fv = (lane == 9) ? 0.f : NEGV;   // START = 9
  const float* fb = feats + (size_t)b * SS * TT;

  for (int s = 0; s < SS; s++) {
    if ((s & 31) == 0) {
      __syncthreads();
      for (int i = lane; i < 32 * TT; i += 64) fch[i] = fb[s * TT + i];
      __syncthreads();
    }
    float best = -3.0e38f; int arg = 0;
    #pragma unroll
    for (int p = 0; p < TT; p++) {
      float v = __shfl(fv, p, 64) + trr[p];
      if (v > best) { best = v; arg = p; }   // strict > keeps FIRST max (numpy argmax)
    }
    if (lane < TT) bp[s][lane] = (unsigned char)arg;
    fv = best + fch[(s & 31) * TT + ln];
  }
  float term = fv + tr[10 * TT + ln];        // STOP = 10
  float best = -3.0e38f; int arg = 0;
  #pragma unroll
  for (int p = 0; p < TT; p++) {
    float v = __shfl(term, p, 64);
    if (v > best) { best = v; arg = p; }
  }
  __syncthreads();
  if (lane == 0) {
    out[b] = best;
    int tg = arg;
    path[SS - 1] = (unsigned char)tg;
    for (int s = SS - 1; s >= 1; s--) {
      tg = bp[s][tg];
      path[s - 1] = (unsigned char)tg;
    }
  }
  __syncthreads();
  for (int i = lane; i < SS; i += 64) out[32 + b * SS + i] = (float)path[i];
}

// ---------------- launcher ----------------
extern "C" void kernel_launch(void* const* d_in, const int* in_sizes, int n_in,
                              void* d_out, int out_size, void* d_ws, size_t ws_size,
                              hipStream_t stream) {
  const int*   x     = (const int*)d_in[0];
  const float* emb   = (const float*)d_in[2];
  const float* wih0f = (const float*)d_in[3];
  const float* whh0f = (const float*)d_in[4];
  const float* b0f   = (const float*)d_in[5];
  const float* wih0b = (const float*)d_in[6];
  const float* whh0b = (const float*)d_in[7];
  const float* b0b   = (const float*)d_in[8];
  const float* wih1f = (const float*)d_in[9];
  const float* whh1f = (const float*)d_in[10];
  const float* b1f   = (const float*)d_in[11];
  const float* wih1b = (const float*)d_in[12];
  const float* whh1b = (const float*)d_in[13];
  const float* b1b   = (const float*)d_in[14];
  const float* wout  = (const float*)d_in[15];
  const float* bout  = (const float*)d_in[16];
  const float* trans = (const float*)d_in[17];

  char* ws = (char*)d_ws;
  unsigned short* xeh = (unsigned short*)(ws + OFF_XEH);
  unsigned short* xel = (unsigned short*)(ws + OFF_XEL);
  float* xs    = (float*)(ws + OFF_XS);
  float* h1    = (float*)(ws + OFF_H0);                     // scan1 f32 output
  unsigned short* h0h = (unsigned short*)(ws + OFF_H1);     // scan0 bf16 hi
  unsigned short* h0l = (unsigned short*)(ws + OFF_H1 + 16777216ull);
  float* feats = (float*)(ws + OFF_FEATS);
  ull* hmb = (ull*)(ws + OFF_HGRP);
  unsigned short* w0h = (unsigned short*)(ws + OFF_W0H);
  unsigned short* w0l = (unsigned short*)(ws + OFF_W0L);
  unsigned short* w1h = (unsigned short*)(ws + OFF_W1H);
  unsigned short* w1l = (unsigned short*)(ws + OFF_W1L);
  float* outp  = (float*)d_out;

  // embedding gather + hi/lo split
  emb_kernel<<<4096, 256, 0, stream>>>(x, (const float4*)emb, (ushort4*)xeh, (ushort4*)xel);
  // fused weight splits: wih0 [2][1024][256], wih1 [2][1024][512]
  split4_kernel<<<1536, 256, 0, stream>>>((const float4*)wih0f, (const float4*)wih0b,
                                          (const float4*)wih1f, (const float4*)wih1b,
                                          (ushort4*)w0h, (ushort4*)w0l,
                                          (ushort4*)w1h, (ushort4*)w1l);

  proj_mfma<256><<<dim3(256, 8, 2), 256, 0, stream>>>(xeh, xel, w0h, w0l, b0f, b0b, xs);
  hipMemsetAsync(hmb, 0, 262144, stream);   // guards first-iteration garbage; scan0 tags 1..512
  scan_kernel<1, 0><<<dim3(8, 16, 2), 256, 0, stream>>>(xs, whh0f, whh0b, hmb,
                                                        nullptr, h0h, h0l);

  proj_mfma<512><<<dim3(256, 8, 2), 256, 0, stream>>>(h0h, h0l, w1h, w1l, b1f, b1b, xs);
  // no memset: scan1 uses tags 1000+s; scan0 overwrote every slot with tags <=512
  scan_kernel<0, 1000><<<dim3(8, 16, 2), 256, 0, stream>>>(xs, whh1f, whh1b, hmb,
                                                           h1, nullptr, nullptr);

  feats_kernel<<<BB * SS, 64, 0, stream>>>(h1, wout, bout, feats);
  viterbi_kernel<<<BB, 64, 0, stream>>>(feats, trans, outp);
}